// Round 13
// baseline (841.486 us; speedup 1.0000x reference)
//
#include <hip/hip_runtime.h>
#include <cstdint>
#include <cstddef>

#define B_      16
#define N_      4096
#define CFEAT_  64
#define NPOINT_ 1024
#define NSAMPLE_ 32
#define CIN_    67
#define KPAD_   96
#define COUT_   128
#define R2_     0.04f
#define NTASK_  (B_ * (NPOINT_ / 4))
#define SCOPE_  __HIP_MEMORY_SCOPE_AGENT
#define FUSE_BID 16
#define GRID_   144

typedef float f32x2 __attribute__((ext_vector_type(2)));
typedef float f32x4 __attribute__((ext_vector_type(4)));
typedef short bf16x8 __attribute__((ext_vector_type(8)));

// Packed f32 ops (VOP3P). Elementwise IEEE-identical to scalar; sub = add(-b).
__device__ __forceinline__ f32x2 pk_sub(f32x2 a, f32x2 b) {
  f32x2 d;
  asm("v_pk_add_f32 %0, %1, %2 neg_lo:[0,1] neg_hi:[0,1]" : "=v"(d) : "v"(a), "v"(b));
  return d;
}
__device__ __forceinline__ f32x2 pk_mul(f32x2 a, f32x2 b) {
  f32x2 d;
  asm("v_pk_mul_f32 %0, %1, %2" : "=v"(d) : "v"(a), "v"(b));
  return d;
}
__device__ __forceinline__ f32x2 pk_add(f32x2 a, f32x2 b) {
  f32x2 d;
  asm("v_pk_add_f32 %0, %1, %2" : "=v"(d) : "v"(a), "v"(b));
  return d;
}
__device__ __forceinline__ float max3f(float a, float b, float c) {
  float r;
  asm("v_max3_f32 %0, %1, %2, %3" : "=v"(r) : "v"(a), "v"(b), "v"(c));
  return r;
}
// RTNE f32 -> bf16
__device__ __forceinline__ unsigned short f2bf(float f) {
  uint32_t u = __float_as_uint(f);
  uint32_t r = (u + 0x7FFFu + ((u >> 16) & 1u)) >> 16;
  return (unsigned short)r;
}
template<int CTRL>
__device__ __forceinline__ float dpp_fmax(float v) {
  int s = __builtin_amdgcn_update_dpp(__float_as_int(v), __float_as_int(v),
                                      CTRL, 0xF, 0xF, false);
  return fmaxf(v, __int_as_float(s));
}

// ---------------- MEGA: blocks 0..15 = FPS producers (round-4 numerics, r10
// publish scheme + publisher ROTATION across waves); block 16 = weight-fuse
// then worker; all blocks then consume group tasks. Cross-block handoffs via
// agent-scope atomics (coherence point).
__global__ __launch_bounds__(256) void k_mega(
    const float* __restrict__ xyz, const float* __restrict__ feat,
    const float* __restrict__ W1, const float* __restrict__ b1,
    const float* __restrict__ W2, const float* __restrict__ b2,
    const float* __restrict__ W3, const float* __restrict__ b3,
    int* __restrict__ ctrl, int* __restrict__ progress,
    unsigned short* __restrict__ Wbf, float* __restrict__ beff,
    float* __restrict__ out_newxyz, float* __restrict__ out_fpsf,
    float* __restrict__ outF) {
  __shared__ __align__(16) char smem[65712];
  __shared__ int tsk_sh;
  const int bid = blockIdx.x, t = threadIdx.x;
  const int w = t >> 6, lane = t & 63;

  if (bid < B_) {
    // ================= FPS (producer) =================
    const int b = bid;
    float* Xsh  = (float*)smem;                    // 48 KB
    float4* res = (float4*)(smem + 49152);         // 16 KB (x,y,z,idx)
    float4* redA = (float4*)(smem + 65536);        // [2][4]
    int*    redI = (int*)(smem + 65664);           // [2][4]
    uint32_t* nxu = (uint32_t*)(out_newxyz + (size_t)b * NPOINT_ * 3);
    const float* X = xyz + (size_t)b * (N_ * 3);
    for (int i = t; i < (N_ * 3) / 4; i += 256)
      ((float4*)Xsh)[i] = ((const float4*)X)[i];
    __syncthreads();

    const int base = t * 16;
    f32x2 px[8], py[8], pz[8], dist[8];
#pragma unroll
    for (int k = 0; k < 8; ++k) {
      int j = base + 2 * k;
      px[k] = f32x2{Xsh[j * 3 + 0], Xsh[j * 3 + 3]};
      py[k] = f32x2{Xsh[j * 3 + 1], Xsh[j * 3 + 4]};
      pz[k] = f32x2{Xsh[j * 3 + 2], Xsh[j * 3 + 5]};
      dist[k] = f32x2{1e10f, 1e10f};
    }
    float cx = Xsh[0], cy = Xsh[1], cz = Xsh[2];
    if (t == 0) res[0] = make_float4(cx, cy, cz, 0.f);

    for (int it = 1; it < NPOINT_; ++it) {
      // publish previous center; ROTATE publisher wave so each wave's store
      // drain (vmcnt at barrier) happens only every 4th iteration
      if (lane == 0 && w == (it & 3)) {
        int c = it - 1;
        __hip_atomic_store(&nxu[c * 3 + 0], __float_as_uint(cx), __ATOMIC_RELAXED, SCOPE_);
        __hip_atomic_store(&nxu[c * 3 + 1], __float_as_uint(cy), __ATOMIC_RELAXED, SCOPE_);
        __hip_atomic_store(&nxu[c * 3 + 2], __float_as_uint(cz), __ATOMIC_RELAXED, SCOPE_);
      }
      if (t == 0 && (it & 15) == 1 && it > 1)
        __hip_atomic_store(&progress[b * 16], it - 1, __ATOMIC_RELEASE, SCOPE_);
      // --- dist update: packed, exact reference op order ((dx^2+dy^2)+dz^2), min
      f32x2 cxx = {cx, cx}, cyy = {cy, cy}, czz = {cz, cz};
      {
#pragma clang fp contract(off)
#pragma unroll
        for (int k = 0; k < 8; ++k) {
          f32x2 dx = pk_sub(px[k], cxx);
          f32x2 dy = pk_sub(py[k], cyy);
          f32x2 dz = pk_sub(pz[k], czz);
          f32x2 s = pk_add(pk_add(pk_mul(dx, dx), pk_mul(dy, dy)), pk_mul(dz, dz));
          dist[k].x = fminf(dist[k].x, s.x);
          dist[k].y = fminf(dist[k].y, s.y);
        }
      }
      float m0 = max3f(dist[0].x, dist[0].y, dist[1].x);
      float m1 = max3f(dist[1].y, dist[2].x, dist[2].y);
      float m2 = max3f(dist[3].x, dist[3].y, dist[4].x);
      float m3 = max3f(dist[4].y, dist[5].x, dist[5].y);
      float m4 = max3f(dist[6].x, dist[6].y, dist[7].x);
      float n0 = max3f(m0, m1, m2);
      float n1 = max3f(m3, m4, dist[7].y);
      float bv = fmaxf(n0, n1);

      int jm = 15;
#pragma unroll
      for (int j = 14; j >= 0; --j) {
        float dj = (j & 1) ? dist[j >> 1].y : dist[j >> 1].x;
        jm = (dj == bv) ? j : jm;
      }
      int bi = base + jm;

      float v = bv;
      v = dpp_fmax<0xB1>(v);
      v = dpp_fmax<0x4E>(v);
      v = dpp_fmax<0x141>(v);
      v = dpp_fmax<0x140>(v);
      v = dpp_fmax<0x142>(v);
      v = dpp_fmax<0x143>(v);
      float wmax = __int_as_float(__builtin_amdgcn_readlane(__float_as_int(v), 63));
      unsigned long long msk = __ballot(bv == wmax);
      int winlane = __ffsll((long long)msk) - 1;
      int wbi = __builtin_amdgcn_readlane(bi, winlane);

      int par = it & 1;
      if (lane == 0) {
        float x = Xsh[wbi * 3 + 0], y = Xsh[wbi * 3 + 1], z = Xsh[wbi * 3 + 2];
        redA[par * 4 + w] = make_float4(wmax, x, y, z);
        redI[par * 4 + w] = wbi;
      }
      __syncthreads();
      float4 a0 = redA[par * 4 + 0], a1 = redA[par * 4 + 1];
      float4 a2 = redA[par * 4 + 2], a3 = redA[par * 4 + 3];
      int4 ii = *(const int4*)&redI[par * 4];
      bool g01 = a1.x > a0.x, g23 = a3.x > a2.x;
      float4 s01 = g01 ? a1 : a0; int i01 = g01 ? ii.y : ii.x;
      float4 s23 = g23 ? a3 : a2; int i23 = g23 ? ii.w : ii.z;
      bool g = s23.x > s01.x;
      float4 s = g ? s23 : s01; int wi = g ? i23 : i01;
      cx = s.y; cy = s.z; cz = s.w;
      if (t == 0) res[it] = make_float4(cx, cy, cz, (float)wi);
    }
    if (t == 0) {   // final center + final publish (release orders prior stores)
      __hip_atomic_store(&nxu[1023 * 3 + 0], __float_as_uint(cx), __ATOMIC_RELAXED, SCOPE_);
      __hip_atomic_store(&nxu[1023 * 3 + 1], __float_as_uint(cy), __ATOMIC_RELAXED, SCOPE_);
      __hip_atomic_store(&nxu[1023 * 3 + 2], __float_as_uint(cz), __ATOMIC_RELAXED, SCOPE_);
      __hip_atomic_store(&progress[b * 16], NPOINT_, __ATOMIC_RELEASE, SCOPE_);
    }
    __syncthreads();
    float* nf = out_fpsf + (size_t)b * NPOINT_;
    for (int i = t; i < NPOINT_; i += 256) nf[i] = res[i].w;
  } else if (bid == FUSE_BID) {
    // ================= FUSE (once, then worker) =================
    float* W21 = (float*)smem;                     // [64][CIN_] = 17152 B
    float* b21 = (float*)(smem + 64 * CIN_ * 4);   // 256 B
    for (int i = t; i < 64 * CIN_; i += 256) {
      int o = i / CIN_, c = i - o * CIN_;
      float s = 0.f;
      for (int j = 0; j < 64; ++j) s = fmaf(W2[o * 64 + j], W1[j * CIN_ + c], s);
      W21[o * CIN_ + c] = s;
    }
    if (t < 64) {
      float s = b2[t];
      for (int j = 0; j < 64; ++j) s = fmaf(W2[t * 64 + j], b1[j], s);
      b21[t] = s;
    }
    __syncthreads();
    // W_eff = W3*W21, bf16, PERMUTED cols: [feat(64) | relxyz(3) | pad(29)]
    for (int i = t; i < COUT_ * (KPAD_ / 2); i += 256) {
      int o = i / (KPAD_ / 2), cp = i - o * (KPAD_ / 2);
      int c0 = 2 * cp, c1 = c0 + 1;
      int s0i = (c0 < 64) ? c0 + 3 : ((c0 < 67) ? c0 - 64 : -1);
      int s1i = (c1 < 64) ? c1 + 3 : ((c1 < 67) ? c1 - 64 : -1);
      float s0 = 0.f, s1 = 0.f;
      if (s0i >= 0) {
        float a = 0.f;
        for (int j = 0; j < 64; ++j) a = fmaf(W3[o * 64 + j], W21[j * CIN_ + s0i], a);
        s0 = a;
      }
      if (s1i >= 0) {
        float a = 0.f;
        for (int j = 0; j < 64; ++j) a = fmaf(W3[o * 64 + j], W21[j * CIN_ + s1i], a);
        s1 = a;
      }
      uint32_t pk = (uint32_t)f2bf(s0) | ((uint32_t)f2bf(s1) << 16);
      ((uint32_t*)Wbf)[o * (KPAD_ / 2) + cp] = pk;
    }
    if (t < COUT_) {
      float s = b3[t];
      for (int j = 0; j < 64; ++j) s = fmaf(W3[t * 64 + j], b21[j], s);
      beff[t] = s;
    }
    __syncthreads();   // all fuse stores complete (vmcnt drained per wave)
    if (t == 0)        // release -> Wbf/beff visible device-wide
      __hip_atomic_store(&ctrl[32], 1, __ATOMIC_RELEASE, SCOPE_);
  }

  // ================= WORKER (consumer) =================
  unsigned short* Wl = (unsigned short*)smem;                  // 24576 B
  unsigned short* gl = (unsigned short*)(smem + 24576);        // 24576 B
  int*   idxs = (int*)(smem + 49152);                          // 512 B
  float* ctrv = (float*)(smem + 49664);                        // [4][3]
  float* bsh  = (float*)(smem + 49712);                        // 512 B
  float (*outsh)[COUT_] = (float(*)[COUT_])(smem + 50224);     // [4][128]
  bool staged = false;
  // loop-top barrier protects res/idxs LDS overlap for fps/fuse blocks
  for (;;) {
    __syncthreads();
    if (t == 0) tsk_sh = atomicAdd(&ctrl[0], 1);
    __syncthreads();
    int task = tsk_sh;
    if (task >= NTASK_) break;
    int tile = task >> 4;          // 0..255, tile-major across batches
    int bb = task & 15;
    int sbase = tile * 4;
    // one-time: wait for fuse, then stage W/bias into LDS
    if (!staged) {
      if (t == 0) {
        while (__hip_atomic_load(&ctrl[32], __ATOMIC_ACQUIRE, SCOPE_) == 0)
          __builtin_amdgcn_s_sleep(2);
      }
      __syncthreads();
      for (int i = t; i < (COUT_ * KPAD_ * 2) / 16; i += 256)
        ((float4*)Wl)[i] = ((const float4*)Wbf)[i];
      if (t < COUT_) bsh[t] = beff[t];
      staged = true;
    }
    if (t == 0) {
      int need = 4 * tile + 4;
      int spins = 0;
      while (__hip_atomic_load(&progress[bb * 16], __ATOMIC_ACQUIRE, SCOPE_) < need) {
        __builtin_amdgcn_s_sleep(2);
        if (++spins > (1 << 24)) break;   // safety valve (never expected)
      }
    }
    __syncthreads();
    // zero gl channels 68..95 (rest fully overwritten below)
    for (int i = t; i < 128 * 7; i += 256) {
      int n = i / 7, k = i - n * 7;
      *(uint2*)((char*)gl + n * (KPAD_ * 2) + 136 + k * 8) = make_uint2(0u, 0u);
    }
    // ---- phase 1: ball query (AoS xyz, 1-deep prefetch), centers via atomics
    {
#pragma clang fp contract(off)
      const float* X = xyz + (size_t)bb * (N_ * 3);
      int s = bb * NPOINT_ + sbase + w;
      uint32_t* cp = (uint32_t*)(out_newxyz) + (size_t)s * 3;
      float cx = __uint_as_float(__hip_atomic_load(&cp[0], __ATOMIC_RELAXED, SCOPE_));
      float cy = __uint_as_float(__hip_atomic_load(&cp[1], __ATOMIC_RELAXED, SCOPE_));
      float cz = __uint_as_float(__hip_atomic_load(&cp[2], __ATOMIC_RELAXED, SCOPE_));
      if (lane == 0) { ctrv[w * 3 + 0] = cx; ctrv[w * 3 + 1] = cy; ctrv[w * 3 + 2] = cz; }
      int total = 0, first = 0;
      float xx = X[lane * 3 + 0], yy = X[lane * 3 + 1], zz = X[lane * 3 + 2];
      int j = 0;
      while (true) {
        int jn = j + 1;
        float nx2 = 0.f, ny2 = 0.f, nz2 = 0.f;
        if (jn < N_ / 64) {
          int pn = jn * 64 + lane;
          nx2 = X[pn * 3 + 0]; ny2 = X[pn * 3 + 1]; nz2 = X[pn * 3 + 2];
        }
        float dx = xx - cx, dy = yy - cy, dz = zz - cz;
        float t0v = dx * dx, t1v = dy * dy, t2v = dz * dz;
        float d = (t0v + t1v) + t2v;
        bool inb = !(d > R2_);
        unsigned long long mask = __ballot(inb);
        if (total == 0 && mask) first = j * 64 + (__ffsll((long long)mask) - 1);
        if (inb) {
          int slot = total + __popcll(mask & ((1ull << lane) - 1ull));
          if (slot < NSAMPLE_) idxs[w * NSAMPLE_ + slot] = j * 64 + lane;
        }
        total += (int)__popcll(mask);
        if (total >= NSAMPLE_ || jn >= N_ / 64) break;
        xx = nx2; yy = ny2; zz = nz2; j = jn;
      }
      for (int slot = total + lane; slot < NSAMPLE_; slot += 64)
        idxs[w * NSAMPLE_ + slot] = first;
    }
    __syncthreads();

    // ---- phase 2: gather. feat -> ch 0..63 (float4); relxyz -> ch 64..66
    for (int i = t; i < 128 * 16; i += 256) {
      int n = i >> 4, cg = i & 15;
      int p = idxs[n];
      float4 f = *(const float4*)(feat + (((size_t)bb * N_ + p) * CFEAT_) + 4 * cg);
      uint32_t lo = (uint32_t)f2bf(f.x) | ((uint32_t)f2bf(f.y) << 16);
      uint32_t hi = (uint32_t)f2bf(f.z) | ((uint32_t)f2bf(f.w) << 16);
      *(uint2*)((char*)gl + n * (KPAD_ * 2) + cg * 8) = make_uint2(lo, hi);
    }
    if (t < 128) {
      int n = t, p = idxs[n];
      const float* Xp = xyz + ((size_t)bb * N_ + p) * 3;
      float x = Xp[0] - ctrv[(n >> 5) * 3 + 0];
      float y = Xp[1] - ctrv[(n >> 5) * 3 + 1];
      float z = Xp[2] - ctrv[(n >> 5) * 3 + 2];
      uint32_t lo = (uint32_t)f2bf(x) | ((uint32_t)f2bf(y) << 16);
      uint32_t hi = (uint32_t)f2bf(z);
      *(uint2*)((char*)gl + n * (KPAD_ * 2) + 128) = make_uint2(lo, hi);
    }
    __syncthreads();

    // ---- phase 3: MFMA 16x16x32 bf16. Wave w -> output rows [32w, 32w+32).
    int q = lane >> 4, c16 = lane & 15;
    f32x4 acc[2][8];
#pragma unroll
    for (int tm = 0; tm < 2; ++tm)
#pragma unroll
      for (int tn = 0; tn < 8; ++tn)
#pragma unroll
        for (int j = 0; j < 4; ++j) acc[tm][tn][j] = 0.f;
    const char* Wb = (const char*)Wl;
    const char* Gb = (const char*)gl;
#pragma unroll
    for (int ks = 0; ks < 3; ++ks) {
      int cb = q * 16 + ks * 64;
      bf16x8 a0 = *(const bf16x8*)(Wb + (32 * w + c16) * (KPAD_ * 2) + cb);
      bf16x8 a1 = *(const bf16x8*)(Wb + (32 * w + 16 + c16) * (KPAD_ * 2) + cb);
#pragma unroll
      for (int tn = 0; tn < 8; ++tn) {
        bf16x8 bbv = *(const bf16x8*)(Gb + (16 * tn + c16) * (KPAD_ * 2) + cb);
        acc[0][tn] = __builtin_amdgcn_mfma_f32_16x16x32_bf16(a0, bbv, acc[0][tn], 0, 0, 0);
        acc[1][tn] = __builtin_amdgcn_mfma_f32_16x16x32_bf16(a1, bbv, acc[1][tn], 0, 0, 0);
      }
    }
    // ---- phase 4: max over 32 samples per center, write out
#pragma unroll
    for (int tm = 0; tm < 2; ++tm) {
#pragma unroll
      for (int si = 0; si < 4; ++si) {
        f32x4 mx;
#pragma unroll
        for (int j = 0; j < 4; ++j)
          mx[j] = fmaxf(acc[tm][2 * si][j], acc[tm][2 * si + 1][j]);
#pragma unroll
        for (int off = 1; off <= 8; off <<= 1) {
#pragma unroll
          for (int j = 0; j < 4; ++j) mx[j] = fmaxf(mx[j], __shfl_xor(mx[j], off));
        }
        if (c16 == 0)
          *(f32x4*)&outsh[si][32 * w + 16 * tm + 4 * q] = mx;
      }
    }
    __syncthreads();
    if (t < COUT_) {
      float bb2 = bsh[t];
      float4 vv = make_float4(outsh[0][t] + bb2, outsh[1][t] + bb2,
                              outsh[2][t] + bb2, outsh[3][t] + bb2);
      *(float4*)&outF[((size_t)bb * COUT_ + t) * NPOINT_ + sbase] = vv;
    }
  }
}

extern "C" void kernel_launch(void* const* d_in, const int* in_sizes, int n_in,
                              void* d_out, int out_size, void* d_ws, size_t ws_size,
                              hipStream_t stream) {
  (void)in_sizes; (void)n_in; (void)out_size; (void)ws_size;
  const float* xyz  = (const float*)d_in[0];
  const float* feat = (const float*)d_in[1];
  const float* W1 = (const float*)d_in[2];
  const float* b1 = (const float*)d_in[3];
  const float* W2 = (const float*)d_in[4];
  const float* b2 = (const float*)d_in[5];
  const float* W3 = (const float*)d_in[6];
  const float* b3 = (const float*)d_in[7];

  float* out = (float*)d_out;
  float* out_newxyz = out;                                        // 16*1024*3
  float* out_feat   = out + (size_t)B_ * NPOINT_ * 3;             // 16*128*1024
  float* out_fpsf   = out_feat + (size_t)B_ * COUT_ * NPOINT_;    // 16*1024

  char* ws = (char*)d_ws;
  int* ctrl = (int*)ws;                                           // [0]=qhead, [32]=fuse_done
  int* progress = (int*)(ws + 256);                               // [b*16]
  unsigned short* Wbf = (unsigned short*)(ws + 1536);             // 24576 B
  float* beff = (float*)(ws + 1536 + 24576);

  hipMemsetAsync(ws, 0, 1536, stream);
  k_mega<<<GRID_, 256, 0, stream>>>(xyz, feat, W1, b1, W2, b2, W3, b3,
                                    ctrl, progress, Wbf, beff,
                                    out_newxyz, out_fpsf, out_feat);
}

// Round 14
// 795.015 us; speedup vs baseline: 1.0585x; 1.0585x over previous
//
#include <hip/hip_runtime.h>
#include <cstdint>
#include <cstddef>

#define B_      16
#define N_      4096
#define CFEAT_  64
#define NPOINT_ 1024
#define NSAMPLE_ 32
#define CIN_    67
#define KPAD_   96
#define COUT_   128
#define R2_     0.04f
#define NTASK_  (B_ * (NPOINT_ / 4))
#define SCOPE_  __HIP_MEMORY_SCOPE_AGENT
#define FUSE_BID 16

typedef float f32x2 __attribute__((ext_vector_type(2)));
typedef float f32x4 __attribute__((ext_vector_type(4)));
typedef short bf16x8 __attribute__((ext_vector_type(8)));

// Packed f32 ops (VOP3P). Elementwise IEEE-identical to scalar; sub = add(-b).
__device__ __forceinline__ f32x2 pk_sub(f32x2 a, f32x2 b) {
  f32x2 d;
  asm("v_pk_add_f32 %0, %1, %2 neg_lo:[0,1] neg_hi:[0,1]" : "=v"(d) : "v"(a), "v"(b));
  return d;
}
__device__ __forceinline__ f32x2 pk_mul(f32x2 a, f32x2 b) {
  f32x2 d;
  asm("v_pk_mul_f32 %0, %1, %2" : "=v"(d) : "v"(a), "v"(b));
  return d;
}
__device__ __forceinline__ f32x2 pk_add(f32x2 a, f32x2 b) {
  f32x2 d;
  asm("v_pk_add_f32 %0, %1, %2" : "=v"(d) : "v"(a), "v"(b));
  return d;
}
__device__ __forceinline__ float max3f(float a, float b, float c) {
  float r;
  asm("v_max3_f32 %0, %1, %2, %3" : "=v"(r) : "v"(a), "v"(b), "v"(c));
  return r;
}
// RTNE f32 -> bf16
__device__ __forceinline__ unsigned short f2bf(float f) {
  uint32_t u = __float_as_uint(f);
  uint32_t r = (u + 0x7FFFu + ((u >> 16) & 1u)) >> 16;
  return (unsigned short)r;
}
template<int CTRL>
__device__ __forceinline__ float dpp_fmax(float v) {
  int s = __builtin_amdgcn_update_dpp(__float_as_int(v), __float_as_int(v),
                                      CTRL, 0xF, 0xF, false);
  return fmaxf(v, __int_as_float(s));
}

// ---------------- MEGA: block 0..15 = FPS producers (round-4 numerics, r10
// publish scheme); block 16 = weight-fuse then worker; all blocks then consume
// group tasks. Cross-block handoffs via agent-scope atomics (coherence point).
__global__ __launch_bounds__(256) void k_mega(
    const float* __restrict__ xyz, const float* __restrict__ feat,
    const float* __restrict__ W1, const float* __restrict__ b1,
    const float* __restrict__ W2, const float* __restrict__ b2,
    const float* __restrict__ W3, const float* __restrict__ b3,
    int* __restrict__ ctrl, int* __restrict__ progress,
    unsigned short* __restrict__ Wbf, float* __restrict__ beff,
    float* __restrict__ out_newxyz, float* __restrict__ out_fpsf,
    float* __restrict__ outF) {
  __shared__ __align__(16) char smem[65712];
  __shared__ int tsk_sh;
  const int bid = blockIdx.x, t = threadIdx.x;
  const int w = t >> 6, lane = t & 63;

  if (bid < B_) {
    // ================= FPS (producer), round-10 scheme =================
    const int b = bid;
    float* Xsh  = (float*)smem;                    // 48 KB
    float4* res = (float4*)(smem + 49152);         // 16 KB (x,y,z,idx)
    float4* redA = (float4*)(smem + 65536);        // [2][4]
    int*    redI = (int*)(smem + 65664);           // [2][4]
    uint32_t* nxu = (uint32_t*)(out_newxyz + (size_t)b * NPOINT_ * 3);
    const float* X = xyz + (size_t)b * (N_ * 3);
    for (int i = t; i < (N_ * 3) / 4; i += 256)
      ((float4*)Xsh)[i] = ((const float4*)X)[i];
    __syncthreads();

    const int base = t * 16;
    f32x2 px[8], py[8], pz[8], dist[8];
#pragma unroll
    for (int k = 0; k < 8; ++k) {
      int j = base + 2 * k;
      px[k] = f32x2{Xsh[j * 3 + 0], Xsh[j * 3 + 3]};
      py[k] = f32x2{Xsh[j * 3 + 1], Xsh[j * 3 + 4]};
      pz[k] = f32x2{Xsh[j * 3 + 2], Xsh[j * 3 + 5]};
      dist[k] = f32x2{1e10f, 1e10f};
    }
    float cx = Xsh[0], cy = Xsh[1], cz = Xsh[2];
    if (t == 0) res[0] = make_float4(cx, cy, cz, 0.f);

    for (int it = 1; it < NPOINT_; ++it) {
      // publish previous center (store drains during this iteration)
      if (t == 0) {
        if ((it & 15) == 1 && it > 1)
          __hip_atomic_store(&progress[b * 16], it - 1, __ATOMIC_RELEASE, SCOPE_);
        int c = it - 1;
        __hip_atomic_store(&nxu[c * 3 + 0], __float_as_uint(cx), __ATOMIC_RELAXED, SCOPE_);
        __hip_atomic_store(&nxu[c * 3 + 1], __float_as_uint(cy), __ATOMIC_RELAXED, SCOPE_);
        __hip_atomic_store(&nxu[c * 3 + 2], __float_as_uint(cz), __ATOMIC_RELAXED, SCOPE_);
      }
      // --- dist update: packed, exact reference op order ((dx^2+dy^2)+dz^2), min
      f32x2 cxx = {cx, cx}, cyy = {cy, cy}, czz = {cz, cz};
      {
#pragma clang fp contract(off)
#pragma unroll
        for (int k = 0; k < 8; ++k) {
          f32x2 dx = pk_sub(px[k], cxx);
          f32x2 dy = pk_sub(py[k], cyy);
          f32x2 dz = pk_sub(pz[k], czz);
          f32x2 s = pk_add(pk_add(pk_mul(dx, dx), pk_mul(dy, dy)), pk_mul(dz, dz));
          dist[k].x = fminf(dist[k].x, s.x);
          dist[k].y = fminf(dist[k].y, s.y);
        }
      }
      float m0 = max3f(dist[0].x, dist[0].y, dist[1].x);
      float m1 = max3f(dist[1].y, dist[2].x, dist[2].y);
      float m2 = max3f(dist[3].x, dist[3].y, dist[4].x);
      float m3 = max3f(dist[4].y, dist[5].x, dist[5].y);
      float m4 = max3f(dist[6].x, dist[6].y, dist[7].x);
      float n0 = max3f(m0, m1, m2);
      float n1 = max3f(m3, m4, dist[7].y);
      float bv = fmaxf(n0, n1);

      int jm = 15;
#pragma unroll
      for (int j = 14; j >= 0; --j) {
        float dj = (j & 1) ? dist[j >> 1].y : dist[j >> 1].x;
        jm = (dj == bv) ? j : jm;
      }
      int bi = base + jm;

      float v = bv;
      v = dpp_fmax<0xB1>(v);
      v = dpp_fmax<0x4E>(v);
      v = dpp_fmax<0x141>(v);
      v = dpp_fmax<0x140>(v);
      v = dpp_fmax<0x142>(v);
      v = dpp_fmax<0x143>(v);
      float wmax = __int_as_float(__builtin_amdgcn_readlane(__float_as_int(v), 63));
      unsigned long long msk = __ballot(bv == wmax);
      int winlane = __ffsll((long long)msk) - 1;
      int wbi = __builtin_amdgcn_readlane(bi, winlane);

      int par = it & 1;
      if (lane == 0) {
        float x = Xsh[wbi * 3 + 0], y = Xsh[wbi * 3 + 1], z = Xsh[wbi * 3 + 2];
        redA[par * 4 + w] = make_float4(wmax, x, y, z);
        redI[par * 4 + w] = wbi;
      }
      __syncthreads();
      float4 a0 = redA[par * 4 + 0], a1 = redA[par * 4 + 1];
      float4 a2 = redA[par * 4 + 2], a3 = redA[par * 4 + 3];
      int4 ii = *(const int4*)&redI[par * 4];
      bool g01 = a1.x > a0.x, g23 = a3.x > a2.x;
      float4 s01 = g01 ? a1 : a0; int i01 = g01 ? ii.y : ii.x;
      float4 s23 = g23 ? a3 : a2; int i23 = g23 ? ii.w : ii.z;
      bool g = s23.x > s01.x;
      float4 s = g ? s23 : s01; int wi = g ? i23 : i01;
      cx = s.y; cy = s.z; cz = s.w;
      if (t == 0) res[it] = make_float4(cx, cy, cz, (float)wi);
    }
    if (t == 0) {   // final center + final publish (release drains the stores)
      __hip_atomic_store(&nxu[1023 * 3 + 0], __float_as_uint(cx), __ATOMIC_RELAXED, SCOPE_);
      __hip_atomic_store(&nxu[1023 * 3 + 1], __float_as_uint(cy), __ATOMIC_RELAXED, SCOPE_);
      __hip_atomic_store(&nxu[1023 * 3 + 2], __float_as_uint(cz), __ATOMIC_RELAXED, SCOPE_);
      __hip_atomic_store(&progress[b * 16], NPOINT_, __ATOMIC_RELEASE, SCOPE_);
    }
    __syncthreads();
    float* nf = out_fpsf + (size_t)b * NPOINT_;
    for (int i = t; i < NPOINT_; i += 256) nf[i] = res[i].w;
  } else if (bid == FUSE_BID) {
    // ================= FUSE (once, then worker) =================
    float* W21 = (float*)smem;                     // [64][CIN_] = 17152 B
    float* b21 = (float*)(smem + 64 * CIN_ * 4);   // 256 B
    for (int i = t; i < 64 * CIN_; i += 256) {
      int o = i / CIN_, c = i - o * CIN_;
      float s = 0.f;
      for (int j = 0; j < 64; ++j) s = fmaf(W2[o * 64 + j], W1[j * CIN_ + c], s);
      W21[o * CIN_ + c] = s;
    }
    if (t < 64) {
      float s = b2[t];
      for (int j = 0; j < 64; ++j) s = fmaf(W2[t * 64 + j], b1[j], s);
      b21[t] = s;
    }
    __syncthreads();
    // W_eff = W3*W21, bf16, PERMUTED cols: [feat(64) | relxyz(3) | pad(29)]
    for (int i = t; i < COUT_ * (KPAD_ / 2); i += 256) {
      int o = i / (KPAD_ / 2), cp = i - o * (KPAD_ / 2);
      int c0 = 2 * cp, c1 = c0 + 1;
      int s0i = (c0 < 64) ? c0 + 3 : ((c0 < 67) ? c0 - 64 : -1);
      int s1i = (c1 < 64) ? c1 + 3 : ((c1 < 67) ? c1 - 64 : -1);
      float s0 = 0.f, s1 = 0.f;
      if (s0i >= 0) {
        float a = 0.f;
        for (int j = 0; j < 64; ++j) a = fmaf(W3[o * 64 + j], W21[j * CIN_ + s0i], a);
        s0 = a;
      }
      if (s1i >= 0) {
        float a = 0.f;
        for (int j = 0; j < 64; ++j) a = fmaf(W3[o * 64 + j], W21[j * CIN_ + s1i], a);
        s1 = a;
      }
      uint32_t pk = (uint32_t)f2bf(s0) | ((uint32_t)f2bf(s1) << 16);
      ((uint32_t*)Wbf)[o * (KPAD_ / 2) + cp] = pk;
    }
    if (t < COUT_) {
      float s = b3[t];
      for (int j = 0; j < 64; ++j) s = fmaf(W3[t * 64 + j], b21[j], s);
      beff[t] = s;
    }
    __syncthreads();   // all fuse stores complete (vmcnt drained per wave)
    if (t == 0)        // release: L2 writeback -> Wbf/beff visible device-wide
      __hip_atomic_store(&ctrl[32], 1, __ATOMIC_RELEASE, SCOPE_);
  }

  // ================= WORKER (consumer) =================
  unsigned short* Wl = (unsigned short*)smem;                  // 24576 B
  unsigned short* gl = (unsigned short*)(smem + 24576);        // 24576 B
  int*   idxs = (int*)(smem + 49152);                          // 512 B
  float* ctrv = (float*)(smem + 49664);                        // [4][3]
  float* bsh  = (float*)(smem + 49712);                        // 512 B
  float (*outsh)[COUT_] = (float(*)[COUT_])(smem + 50224);     // [4][128]
  bool staged = false;
  // loop-top barrier protects res/idxs LDS overlap for fps/fuse blocks
  for (;;) {
    __syncthreads();
    if (t == 0) tsk_sh = atomicAdd(&ctrl[0], 1);
    __syncthreads();
    int task = tsk_sh;
    if (task >= NTASK_) break;
    int tile = task >> 4;          // 0..255, tile-major across batches
    int bb = task & 15;
    int sbase = tile * 4;
    // one-time: wait for fuse, then stage W/bias into LDS
    if (!staged) {
      if (t == 0) {
        while (__hip_atomic_load(&ctrl[32], __ATOMIC_ACQUIRE, SCOPE_) == 0)
          __builtin_amdgcn_s_sleep(2);
      }
      __syncthreads();
      for (int i = t; i < (COUT_ * KPAD_ * 2) / 16; i += 256)
        ((float4*)Wl)[i] = ((const float4*)Wbf)[i];
      if (t < COUT_) bsh[t] = beff[t];
      staged = true;
    }
    if (t == 0) {
      int need = 4 * tile + 4;
      int spins = 0;
      while (__hip_atomic_load(&progress[bb * 16], __ATOMIC_ACQUIRE, SCOPE_) < need) {
        __builtin_amdgcn_s_sleep(2);
        if (++spins > (1 << 24)) break;   // safety valve (never expected)
      }
    }
    __syncthreads();
    // zero gl channels 68..95 (rest fully overwritten below)
    for (int i = t; i < 128 * 7; i += 256) {
      int n = i / 7, k = i - n * 7;
      *(uint2*)((char*)gl + n * (KPAD_ * 2) + 136 + k * 8) = make_uint2(0u, 0u);
    }
    // ---- phase 1: ball query (AoS xyz, 1-deep prefetch), centers via atomics
    {
#pragma clang fp contract(off)
      const float* X = xyz + (size_t)bb * (N_ * 3);
      int s = bb * NPOINT_ + sbase + w;
      uint32_t* cp = (uint32_t*)(out_newxyz) + (size_t)s * 3;
      float cx = __uint_as_float(__hip_atomic_load(&cp[0], __ATOMIC_RELAXED, SCOPE_));
      float cy = __uint_as_float(__hip_atomic_load(&cp[1], __ATOMIC_RELAXED, SCOPE_));
      float cz = __uint_as_float(__hip_atomic_load(&cp[2], __ATOMIC_RELAXED, SCOPE_));
      if (lane == 0) { ctrv[w * 3 + 0] = cx; ctrv[w * 3 + 1] = cy; ctrv[w * 3 + 2] = cz; }
      int total = 0, first = 0;
      float xx = X[lane * 3 + 0], yy = X[lane * 3 + 1], zz = X[lane * 3 + 2];
      int j = 0;
      while (true) {
        int jn = j + 1;
        float nx2 = 0.f, ny2 = 0.f, nz2 = 0.f;
        if (jn < N_ / 64) {
          int pn = jn * 64 + lane;
          nx2 = X[pn * 3 + 0]; ny2 = X[pn * 3 + 1]; nz2 = X[pn * 3 + 2];
        }
        float dx = xx - cx, dy = yy - cy, dz = zz - cz;
        float t0v = dx * dx, t1v = dy * dy, t2v = dz * dz;
        float d = (t0v + t1v) + t2v;
        bool inb = !(d > R2_);
        unsigned long long mask = __ballot(inb);
        if (total == 0 && mask) first = j * 64 + (__ffsll((long long)mask) - 1);
        if (inb) {
          int slot = total + __popcll(mask & ((1ull << lane) - 1ull));
          if (slot < NSAMPLE_) idxs[w * NSAMPLE_ + slot] = j * 64 + lane;
        }
        total += (int)__popcll(mask);
        if (total >= NSAMPLE_ || jn >= N_ / 64) break;
        xx = nx2; yy = ny2; zz = nz2; j = jn;
      }
      for (int slot = total + lane; slot < NSAMPLE_; slot += 64)
        idxs[w * NSAMPLE_ + slot] = first;
    }
    __syncthreads();

    // ---- phase 2: gather. feat -> ch 0..63 (float4); relxyz -> ch 64..66
    for (int i = t; i < 128 * 16; i += 256) {
      int n = i >> 4, cg = i & 15;
      int p = idxs[n];
      float4 f = *(const float4*)(feat + (((size_t)bb * N_ + p) * CFEAT_) + 4 * cg);
      uint32_t lo = (uint32_t)f2bf(f.x) | ((uint32_t)f2bf(f.y) << 16);
      uint32_t hi = (uint32_t)f2bf(f.z) | ((uint32_t)f2bf(f.w) << 16);
      *(uint2*)((char*)gl + n * (KPAD_ * 2) + cg * 8) = make_uint2(lo, hi);
    }
    if (t < 128) {
      int n = t, p = idxs[n];
      const float* Xp = xyz + ((size_t)bb * N_ + p) * 3;
      float x = Xp[0] - ctrv[(n >> 5) * 3 + 0];
      float y = Xp[1] - ctrv[(n >> 5) * 3 + 1];
      float z = Xp[2] - ctrv[(n >> 5) * 3 + 2];
      uint32_t lo = (uint32_t)f2bf(x) | ((uint32_t)f2bf(y) << 16);
      uint32_t hi = (uint32_t)f2bf(z);
      *(uint2*)((char*)gl + n * (KPAD_ * 2) + 128) = make_uint2(lo, hi);
    }
    __syncthreads();

    // ---- phase 3: MFMA 16x16x32 bf16. Wave w -> output rows [32w, 32w+32).
    int q = lane >> 4, c16 = lane & 15;
    f32x4 acc[2][8];
#pragma unroll
    for (int tm = 0; tm < 2; ++tm)
#pragma unroll
      for (int tn = 0; tn < 8; ++tn)
#pragma unroll
        for (int j = 0; j < 4; ++j) acc[tm][tn][j] = 0.f;
    const char* Wb = (const char*)Wl;
    const char* Gb = (const char*)gl;
#pragma unroll
    for (int ks = 0; ks < 3; ++ks) {
      int cb = q * 16 + ks * 64;
      bf16x8 a0 = *(const bf16x8*)(Wb + (32 * w + c16) * (KPAD_ * 2) + cb);
      bf16x8 a1 = *(const bf16x8*)(Wb + (32 * w + 16 + c16) * (KPAD_ * 2) + cb);
#pragma unroll
      for (int tn = 0; tn < 8; ++tn) {
        bf16x8 bbv = *(const bf16x8*)(Gb + (16 * tn + c16) * (KPAD_ * 2) + cb);
        acc[0][tn] = __builtin_amdgcn_mfma_f32_16x16x32_bf16(a0, bbv, acc[0][tn], 0, 0, 0);
        acc[1][tn] = __builtin_amdgcn_mfma_f32_16x16x32_bf16(a1, bbv, acc[1][tn], 0, 0, 0);
      }
    }
    // ---- phase 4: max over 32 samples per center, write out
#pragma unroll
    for (int tm = 0; tm < 2; ++tm) {
#pragma unroll
      for (int si = 0; si < 4; ++si) {
        f32x4 mx;
#pragma unroll
        for (int j = 0; j < 4; ++j)
          mx[j] = fmaxf(acc[tm][2 * si][j], acc[tm][2 * si + 1][j]);
#pragma unroll
        for (int off = 1; off <= 8; off <<= 1) {
#pragma unroll
          for (int j = 0; j < 4; ++j) mx[j] = fmaxf(mx[j], __shfl_xor(mx[j], off));
        }
        if (c16 == 0)
          *(f32x4*)&outsh[si][32 * w + 16 * tm + 4 * q] = mx;
      }
    }
    __syncthreads();
    if (t < COUT_) {
      float bb2 = bsh[t];
      float4 vv = make_float4(outsh[0][t] + bb2, outsh[1][t] + bb2,
                              outsh[2][t] + bb2, outsh[3][t] + bb2);
      *(float4*)&outF[((size_t)bb * COUT_ + t) * NPOINT_ + sbase] = vv;
    }
  }
}

extern "C" void kernel_launch(void* const* d_in, const int* in_sizes, int n_in,
                              void* d_out, int out_size, void* d_ws, size_t ws_size,
                              hipStream_t stream) {
  (void)in_sizes; (void)n_in; (void)out_size; (void)ws_size;
  const float* xyz  = (const float*)d_in[0];
  const float* feat = (const float*)d_in[1];
  const float* W1 = (const float*)d_in[2];
  const float* b1 = (const float*)d_in[3];
  const float* W2 = (const float*)d_in[4];
  const float* b2 = (const float*)d_in[5];
  const float* W3 = (const float*)d_in[6];
  const float* b3 = (const float*)d_in[7];

  float* out = (float*)d_out;
  float* out_newxyz = out;                                        // 16*1024*3
  float* out_feat   = out + (size_t)B_ * NPOINT_ * 3;             // 16*128*1024
  float* out_fpsf   = out_feat + (size_t)B_ * COUT_ * NPOINT_;    // 16*1024

  char* ws = (char*)d_ws;
  int* ctrl = (int*)ws;                                           // [0]=qhead, [32]=fuse_done
  int* progress = (int*)(ws + 256);                               // [b*16]
  unsigned short* Wbf = (unsigned short*)(ws + 1536);             // 24576 B
  float* beff = (float*)(ws + 1536 + 24576);

  hipMemsetAsync(ws, 0, 1536, stream);
  k_mega<<<256, 256, 0, stream>>>(xyz, feat, W1, b1, W2, b2, W3, b3,
                                  ctrl, progress, Wbf, beff,
                                  out_newxyz, out_fpsf, out_feat);
}

// Round 15
// 790.489 us; speedup vs baseline: 1.0645x; 1.0057x over previous
//
#include <hip/hip_runtime.h>
#include <cstdint>
#include <cstddef>

#define B_      16
#define N_      4096
#define CFEAT_  64
#define NPOINT_ 1024
#define NSAMPLE_ 32
#define CIN_    67
#define KPAD_   96
#define COUT_   128
#define R2_     0.04f
#define NTASK_  (B_ * (NPOINT_ / 4))
#define SCOPE_  __HIP_MEMORY_SCOPE_AGENT
#define FUSE_BID 16

typedef float f32x2 __attribute__((ext_vector_type(2)));
typedef float f32x4 __attribute__((ext_vector_type(4)));
typedef short bf16x8 __attribute__((ext_vector_type(8)));

// Packed f32 ops (VOP3P). Elementwise IEEE-identical to scalar; sub = add(-b).
__device__ __forceinline__ f32x2 pk_sub(f32x2 a, f32x2 b) {
  f32x2 d;
  asm("v_pk_add_f32 %0, %1, %2 neg_lo:[0,1] neg_hi:[0,1]" : "=v"(d) : "v"(a), "v"(b));
  return d;
}
__device__ __forceinline__ f32x2 pk_mul(f32x2 a, f32x2 b) {
  f32x2 d;
  asm("v_pk_mul_f32 %0, %1, %2" : "=v"(d) : "v"(a), "v"(b));
  return d;
}
__device__ __forceinline__ f32x2 pk_add(f32x2 a, f32x2 b) {
  f32x2 d;
  asm("v_pk_add_f32 %0, %1, %2" : "=v"(d) : "v"(a), "v"(b));
  return d;
}
__device__ __forceinline__ float max3f(float a, float b, float c) {
  float r;
  asm("v_max3_f32 %0, %1, %2, %3" : "=v"(r) : "v"(a), "v"(b), "v"(c));
  return r;
}
// RTNE f32 -> bf16
__device__ __forceinline__ unsigned short f2bf(float f) {
  uint32_t u = __float_as_uint(f);
  uint32_t r = (u + 0x7FFFu + ((u >> 16) & 1u)) >> 16;
  return (unsigned short)r;
}
template<int CTRL>
__device__ __forceinline__ float dpp_fmax(float v) {
  int s = __builtin_amdgcn_update_dpp(__float_as_int(v), __float_as_int(v),
                                      CTRL, 0xF, 0xF, false);
  return fmaxf(v, __int_as_float(s));
}

// ---------------- MEGA: block 0..15 = FPS producers (round-4 numerics, r10
// publish scheme); block 16 = weight-fuse then worker; all blocks then consume
// group tasks. Cross-block handoffs via agent-scope atomics (coherence point).
// r15 change: spin probes use s_sleep(64) (~4096 cyc) instead of s_sleep(2) to
// cut cross-XCD coherence traffic from ~240 spinning blocks.
__global__ __launch_bounds__(256) void k_mega(
    const float* __restrict__ xyz, const float* __restrict__ feat,
    const float* __restrict__ W1, const float* __restrict__ b1,
    const float* __restrict__ W2, const float* __restrict__ b2,
    const float* __restrict__ W3, const float* __restrict__ b3,
    int* __restrict__ ctrl, int* __restrict__ progress,
    unsigned short* __restrict__ Wbf, float* __restrict__ beff,
    float* __restrict__ out_newxyz, float* __restrict__ out_fpsf,
    float* __restrict__ outF) {
  __shared__ __align__(16) char smem[65712];
  __shared__ int tsk_sh;
  const int bid = blockIdx.x, t = threadIdx.x;
  const int w = t >> 6, lane = t & 63;

  if (bid < B_) {
    // ================= FPS (producer), round-10 scheme =================
    const int b = bid;
    float* Xsh  = (float*)smem;                    // 48 KB
    float4* res = (float4*)(smem + 49152);         // 16 KB (x,y,z,idx)
    float4* redA = (float4*)(smem + 65536);        // [2][4]
    int*    redI = (int*)(smem + 65664);           // [2][4]
    uint32_t* nxu = (uint32_t*)(out_newxyz + (size_t)b * NPOINT_ * 3);
    const float* X = xyz + (size_t)b * (N_ * 3);
    for (int i = t; i < (N_ * 3) / 4; i += 256)
      ((float4*)Xsh)[i] = ((const float4*)X)[i];
    __syncthreads();

    const int base = t * 16;
    f32x2 px[8], py[8], pz[8], dist[8];
#pragma unroll
    for (int k = 0; k < 8; ++k) {
      int j = base + 2 * k;
      px[k] = f32x2{Xsh[j * 3 + 0], Xsh[j * 3 + 3]};
      py[k] = f32x2{Xsh[j * 3 + 1], Xsh[j * 3 + 4]};
      pz[k] = f32x2{Xsh[j * 3 + 2], Xsh[j * 3 + 5]};
      dist[k] = f32x2{1e10f, 1e10f};
    }
    float cx = Xsh[0], cy = Xsh[1], cz = Xsh[2];
    if (t == 0) res[0] = make_float4(cx, cy, cz, 0.f);

    for (int it = 1; it < NPOINT_; ++it) {
      // publish previous center (store drains during this iteration)
      if (t == 0) {
        if ((it & 15) == 1 && it > 1)
          __hip_atomic_store(&progress[b * 16], it - 1, __ATOMIC_RELEASE, SCOPE_);
        int c = it - 1;
        __hip_atomic_store(&nxu[c * 3 + 0], __float_as_uint(cx), __ATOMIC_RELAXED, SCOPE_);
        __hip_atomic_store(&nxu[c * 3 + 1], __float_as_uint(cy), __ATOMIC_RELAXED, SCOPE_);
        __hip_atomic_store(&nxu[c * 3 + 2], __float_as_uint(cz), __ATOMIC_RELAXED, SCOPE_);
      }
      // --- dist update: packed, exact reference op order ((dx^2+dy^2)+dz^2), min
      f32x2 cxx = {cx, cx}, cyy = {cy, cy}, czz = {cz, cz};
      {
#pragma clang fp contract(off)
#pragma unroll
        for (int k = 0; k < 8; ++k) {
          f32x2 dx = pk_sub(px[k], cxx);
          f32x2 dy = pk_sub(py[k], cyy);
          f32x2 dz = pk_sub(pz[k], czz);
          f32x2 s = pk_add(pk_add(pk_mul(dx, dx), pk_mul(dy, dy)), pk_mul(dz, dz));
          dist[k].x = fminf(dist[k].x, s.x);
          dist[k].y = fminf(dist[k].y, s.y);
        }
      }
      float m0 = max3f(dist[0].x, dist[0].y, dist[1].x);
      float m1 = max3f(dist[1].y, dist[2].x, dist[2].y);
      float m2 = max3f(dist[3].x, dist[3].y, dist[4].x);
      float m3 = max3f(dist[4].y, dist[5].x, dist[5].y);
      float m4 = max3f(dist[6].x, dist[6].y, dist[7].x);
      float n0 = max3f(m0, m1, m2);
      float n1 = max3f(m3, m4, dist[7].y);
      float bv = fmaxf(n0, n1);

      int jm = 15;
#pragma unroll
      for (int j = 14; j >= 0; --j) {
        float dj = (j & 1) ? dist[j >> 1].y : dist[j >> 1].x;
        jm = (dj == bv) ? j : jm;
      }
      int bi = base + jm;

      float v = bv;
      v = dpp_fmax<0xB1>(v);
      v = dpp_fmax<0x4E>(v);
      v = dpp_fmax<0x141>(v);
      v = dpp_fmax<0x140>(v);
      v = dpp_fmax<0x142>(v);
      v = dpp_fmax<0x143>(v);
      float wmax = __int_as_float(__builtin_amdgcn_readlane(__float_as_int(v), 63));
      unsigned long long msk = __ballot(bv == wmax);
      int winlane = __ffsll((long long)msk) - 1;
      int wbi = __builtin_amdgcn_readlane(bi, winlane);

      int par = it & 1;
      if (lane == 0) {
        float x = Xsh[wbi * 3 + 0], y = Xsh[wbi * 3 + 1], z = Xsh[wbi * 3 + 2];
        redA[par * 4 + w] = make_float4(wmax, x, y, z);
        redI[par * 4 + w] = wbi;
      }
      __syncthreads();
      float4 a0 = redA[par * 4 + 0], a1 = redA[par * 4 + 1];
      float4 a2 = redA[par * 4 + 2], a3 = redA[par * 4 + 3];
      int4 ii = *(const int4*)&redI[par * 4];
      bool g01 = a1.x > a0.x, g23 = a3.x > a2.x;
      float4 s01 = g01 ? a1 : a0; int i01 = g01 ? ii.y : ii.x;
      float4 s23 = g23 ? a3 : a2; int i23 = g23 ? ii.w : ii.z;
      bool g = s23.x > s01.x;
      float4 s = g ? s23 : s01; int wi = g ? i23 : i01;
      cx = s.y; cy = s.z; cz = s.w;
      if (t == 0) res[it] = make_float4(cx, cy, cz, (float)wi);
    }
    if (t == 0) {   // final center + final publish (release drains the stores)
      __hip_atomic_store(&nxu[1023 * 3 + 0], __float_as_uint(cx), __ATOMIC_RELAXED, SCOPE_);
      __hip_atomic_store(&nxu[1023 * 3 + 1], __float_as_uint(cy), __ATOMIC_RELAXED, SCOPE_);
      __hip_atomic_store(&nxu[1023 * 3 + 2], __float_as_uint(cz), __ATOMIC_RELAXED, SCOPE_);
      __hip_atomic_store(&progress[b * 16], NPOINT_, __ATOMIC_RELEASE, SCOPE_);
    }
    __syncthreads();
    float* nf = out_fpsf + (size_t)b * NPOINT_;
    for (int i = t; i < NPOINT_; i += 256) nf[i] = res[i].w;
  } else if (bid == FUSE_BID) {
    // ================= FUSE (once, then worker) =================
    float* W21 = (float*)smem;                     // [64][CIN_] = 17152 B
    float* b21 = (float*)(smem + 64 * CIN_ * 4);   // 256 B
    for (int i = t; i < 64 * CIN_; i += 256) {
      int o = i / CIN_, c = i - o * CIN_;
      float s = 0.f;
      for (int j = 0; j < 64; ++j) s = fmaf(W2[o * 64 + j], W1[j * CIN_ + c], s);
      W21[o * CIN_ + c] = s;
    }
    if (t < 64) {
      float s = b2[t];
      for (int j = 0; j < 64; ++j) s = fmaf(W2[t * 64 + j], b1[j], s);
      b21[t] = s;
    }
    __syncthreads();
    // W_eff = W3*W21, bf16, PERMUTED cols: [feat(64) | relxyz(3) | pad(29)]
    for (int i = t; i < COUT_ * (KPAD_ / 2); i += 256) {
      int o = i / (KPAD_ / 2), cp = i - o * (KPAD_ / 2);
      int c0 = 2 * cp, c1 = c0 + 1;
      int s0i = (c0 < 64) ? c0 + 3 : ((c0 < 67) ? c0 - 64 : -1);
      int s1i = (c1 < 64) ? c1 + 3 : ((c1 < 67) ? c1 - 64 : -1);
      float s0 = 0.f, s1 = 0.f;
      if (s0i >= 0) {
        float a = 0.f;
        for (int j = 0; j < 64; ++j) a = fmaf(W3[o * 64 + j], W21[j * CIN_ + s0i], a);
        s0 = a;
      }
      if (s1i >= 0) {
        float a = 0.f;
        for (int j = 0; j < 64; ++j) a = fmaf(W3[o * 64 + j], W21[j * CIN_ + s1i], a);
        s1 = a;
      }
      uint32_t pk = (uint32_t)f2bf(s0) | ((uint32_t)f2bf(s1) << 16);
      ((uint32_t*)Wbf)[o * (KPAD_ / 2) + cp] = pk;
    }
    if (t < COUT_) {
      float s = b3[t];
      for (int j = 0; j < 64; ++j) s = fmaf(W3[t * 64 + j], b21[j], s);
      beff[t] = s;
    }
    __syncthreads();   // all fuse stores complete (vmcnt drained per wave)
    if (t == 0)        // release: L2 writeback -> Wbf/beff visible device-wide
      __hip_atomic_store(&ctrl[32], 1, __ATOMIC_RELEASE, SCOPE_);
  }

  // ================= WORKER (consumer) =================
  unsigned short* Wl = (unsigned short*)smem;                  // 24576 B
  unsigned short* gl = (unsigned short*)(smem + 24576);        // 24576 B
  int*   idxs = (int*)(smem + 49152);                          // 512 B
  float* ctrv = (float*)(smem + 49664);                        // [4][3]
  float* bsh  = (float*)(smem + 49712);                        // 512 B
  float (*outsh)[COUT_] = (float(*)[COUT_])(smem + 50224);     // [4][128]
  bool staged = false;
  // loop-top barrier protects res/idxs LDS overlap for fps/fuse blocks
  for (;;) {
    __syncthreads();
    if (t == 0) tsk_sh = atomicAdd(&ctrl[0], 1);
    __syncthreads();
    int task = tsk_sh;
    if (task >= NTASK_) break;
    int tile = task >> 4;          // 0..255, tile-major across batches
    int bb = task & 15;
    int sbase = tile * 4;
    // one-time: wait for fuse, then stage W/bias into LDS
    if (!staged) {
      if (t == 0) {
        while (__hip_atomic_load(&ctrl[32], __ATOMIC_ACQUIRE, SCOPE_) == 0)
          __builtin_amdgcn_s_sleep(64);
      }
      __syncthreads();
      for (int i = t; i < (COUT_ * KPAD_ * 2) / 16; i += 256)
        ((float4*)Wl)[i] = ((const float4*)Wbf)[i];
      if (t < COUT_) bsh[t] = beff[t];
      staged = true;
    }
    if (t == 0) {
      int need = 4 * tile + 4;
      int spins = 0;
      while (__hip_atomic_load(&progress[bb * 16], __ATOMIC_ACQUIRE, SCOPE_) < need) {
        __builtin_amdgcn_s_sleep(64);
        if (++spins > (1 << 22)) break;   // safety valve (never expected)
      }
    }
    __syncthreads();
    // zero gl channels 68..95 (rest fully overwritten below)
    for (int i = t; i < 128 * 7; i += 256) {
      int n = i / 7, k = i - n * 7;
      *(uint2*)((char*)gl + n * (KPAD_ * 2) + 136 + k * 8) = make_uint2(0u, 0u);
    }
    // ---- phase 1: ball query (AoS xyz, 1-deep prefetch), centers via atomics
    {
#pragma clang fp contract(off)
      const float* X = xyz + (size_t)bb * (N_ * 3);
      int s = bb * NPOINT_ + sbase + w;
      uint32_t* cp = (uint32_t*)(out_newxyz) + (size_t)s * 3;
      float cx = __uint_as_float(__hip_atomic_load(&cp[0], __ATOMIC_RELAXED, SCOPE_));
      float cy = __uint_as_float(__hip_atomic_load(&cp[1], __ATOMIC_RELAXED, SCOPE_));
      float cz = __uint_as_float(__hip_atomic_load(&cp[2], __ATOMIC_RELAXED, SCOPE_));
      if (lane == 0) { ctrv[w * 3 + 0] = cx; ctrv[w * 3 + 1] = cy; ctrv[w * 3 + 2] = cz; }
      int total = 0, first = 0;
      float xx = X[lane * 3 + 0], yy = X[lane * 3 + 1], zz = X[lane * 3 + 2];
      int j = 0;
      while (true) {
        int jn = j + 1;
        float nx2 = 0.f, ny2 = 0.f, nz2 = 0.f;
        if (jn < N_ / 64) {
          int pn = jn * 64 + lane;
          nx2 = X[pn * 3 + 0]; ny2 = X[pn * 3 + 1]; nz2 = X[pn * 3 + 2];
        }
        float dx = xx - cx, dy = yy - cy, dz = zz - cz;
        float t0v = dx * dx, t1v = dy * dy, t2v = dz * dz;
        float d = (t0v + t1v) + t2v;
        bool inb = !(d > R2_);
        unsigned long long mask = __ballot(inb);
        if (total == 0 && mask) first = j * 64 + (__ffsll((long long)mask) - 1);
        if (inb) {
          int slot = total + __popcll(mask & ((1ull << lane) - 1ull));
          if (slot < NSAMPLE_) idxs[w * NSAMPLE_ + slot] = j * 64 + lane;
        }
        total += (int)__popcll(mask);
        if (total >= NSAMPLE_ || jn >= N_ / 64) break;
        xx = nx2; yy = ny2; zz = nz2; j = jn;
      }
      for (int slot = total + lane; slot < NSAMPLE_; slot += 64)
        idxs[w * NSAMPLE_ + slot] = first;
    }
    __syncthreads();

    // ---- phase 2: gather. feat -> ch 0..63 (float4); relxyz -> ch 64..66
    for (int i = t; i < 128 * 16; i += 256) {
      int n = i >> 4, cg = i & 15;
      int p = idxs[n];
      float4 f = *(const float4*)(feat + (((size_t)bb * N_ + p) * CFEAT_) + 4 * cg);
      uint32_t lo = (uint32_t)f2bf(f.x) | ((uint32_t)f2bf(f.y) << 16);
      uint32_t hi = (uint32_t)f2bf(f.z) | ((uint32_t)f2bf(f.w) << 16);
      *(uint2*)((char*)gl + n * (KPAD_ * 2) + cg * 8) = make_uint2(lo, hi);
    }
    if (t < 128) {
      int n = t, p = idxs[n];
      const float* Xp = xyz + ((size_t)bb * N_ + p) * 3;
      float x = Xp[0] - ctrv[(n >> 5) * 3 + 0];
      float y = Xp[1] - ctrv[(n >> 5) * 3 + 1];
      float z = Xp[2] - ctrv[(n >> 5) * 3 + 2];
      uint32_t lo = (uint32_t)f2bf(x) | ((uint32_t)f2bf(y) << 16);
      uint32_t hi = (uint32_t)f2bf(z);
      *(uint2*)((char*)gl + n * (KPAD_ * 2) + 128) = make_uint2(lo, hi);
    }
    __syncthreads();

    // ---- phase 3: MFMA 16x16x32 bf16. Wave w -> output rows [32w, 32w+32).
    int q = lane >> 4, c16 = lane & 15;
    f32x4 acc[2][8];
#pragma unroll
    for (int tm = 0; tm < 2; ++tm)
#pragma unroll
      for (int tn = 0; tn < 8; ++tn)
#pragma unroll
        for (int j = 0; j < 4; ++j) acc[tm][tn][j] = 0.f;
    const char* Wb = (const char*)Wl;
    const char* Gb = (const char*)gl;
#pragma unroll
    for (int ks = 0; ks < 3; ++ks) {
      int cb = q * 16 + ks * 64;
      bf16x8 a0 = *(const bf16x8*)(Wb + (32 * w + c16) * (KPAD_ * 2) + cb);
      bf16x8 a1 = *(const bf16x8*)(Wb + (32 * w + 16 + c16) * (KPAD_ * 2) + cb);
#pragma unroll
      for (int tn = 0; tn < 8; ++tn) {
        bf16x8 bbv = *(const bf16x8*)(Gb + (16 * tn + c16) * (KPAD_ * 2) + cb);
        acc[0][tn] = __builtin_amdgcn_mfma_f32_16x16x32_bf16(a0, bbv, acc[0][tn], 0, 0, 0);
        acc[1][tn] = __builtin_amdgcn_mfma_f32_16x16x32_bf16(a1, bbv, acc[1][tn], 0, 0, 0);
      }
    }
    // ---- phase 4: max over 32 samples per center, write out
#pragma unroll
    for (int tm = 0; tm < 2; ++tm) {
#pragma unroll
      for (int si = 0; si < 4; ++si) {
        f32x4 mx;
#pragma unroll
        for (int j = 0; j < 4; ++j)
          mx[j] = fmaxf(acc[tm][2 * si][j], acc[tm][2 * si + 1][j]);
#pragma unroll
        for (int off = 1; off <= 8; off <<= 1) {
#pragma unroll
          for (int j = 0; j < 4; ++j) mx[j] = fmaxf(mx[j], __shfl_xor(mx[j], off));
        }
        if (c16 == 0)
          *(f32x4*)&outsh[si][32 * w + 16 * tm + 4 * q] = mx;
      }
    }
    __syncthreads();
    if (t < COUT_) {
      float bb2 = bsh[t];
      float4 vv = make_float4(outsh[0][t] + bb2, outsh[1][t] + bb2,
                              outsh[2][t] + bb2, outsh[3][t] + bb2);
      *(float4*)&outF[((size_t)bb * COUT_ + t) * NPOINT_ + sbase] = vv;
    }
  }
}

extern "C" void kernel_launch(void* const* d_in, const int* in_sizes, int n_in,
                              void* d_out, int out_size, void* d_ws, size_t ws_size,
                              hipStream_t stream) {
  (void)in_sizes; (void)n_in; (void)out_size; (void)ws_size;
  const float* xyz  = (const float*)d_in[0];
  const float* feat = (const float*)d_in[1];
  const float* W1 = (const float*)d_in[2];
  const float* b1 = (const float*)d_in[3];
  const float* W2 = (const float*)d_in[4];
  const float* b2 = (const float*)d_in[5];
  const float* W3 = (const float*)d_in[6];
  const float* b3 = (const float*)d_in[7];

  float* out = (float*)d_out;
  float* out_newxyz = out;                                        // 16*1024*3
  float* out_feat   = out + (size_t)B_ * NPOINT_ * 3;             // 16*128*1024
  float* out_fpsf   = out_feat + (size_t)B_ * COUT_ * NPOINT_;    // 16*1024

  char* ws = (char*)d_ws;
  int* ctrl = (int*)ws;                                           // [0]=qhead, [32]=fuse_done
  int* progress = (int*)(ws + 256);                               // [b*16]
  unsigned short* Wbf = (unsigned short*)(ws + 1536);             // 24576 B
  float* beff = (float*)(ws + 1536 + 24576);

  hipMemsetAsync(ws, 0, 1536, stream);
  k_mega<<<256, 256, 0, stream>>>(xyz, feat, W1, b1, W2, b2, W3, b3,
                                  ctrl, progress, Wbf, beff,
                                  out_newxyz, out_fpsf, out_feat);
}